// Round 17
// baseline (451.393 us; speedup 1.0000x reference)
//
#include <hip/hip_runtime.h>
#include <hip/hip_bf16.h>

typedef float f32x4 __attribute__((ext_vector_type(4)));
typedef int i32x4v __attribute__((ext_vector_type(4)));
typedef int i32x8v __attribute__((ext_vector_type(8)));

#define IGNORE_INDEX (-100)
#define N_ROWS 4096
#define H_DIM  1024
#define V_DIM  32000

#define BM 128
#define BN 128
#define BK 128                 /* fp8 elements = bytes; one mfma_scale K */
#define NKT (H_DIM / BK)       /* 8 */
#define CT_NUM (V_DIM / BN)    /* 250 */
#define RT_NUM (N_ROWS / BM)   /* 32 */
#define SCALE1 0x7f7f7f7f      /* 4x e8m0 = 127 -> x1.0 */

// ---------- fused prep: cast x -> fp8 (blocks < XB8) + transpose-cast w ----------
#define XB8 (N_ROWS * H_DIM / (256 * 16))  /* 1024 */
__global__ __launch_bounds__(256) void k_prep(const float* __restrict__ x,
                                              const float* __restrict__ w,
                                              unsigned char* __restrict__ x8,
                                              unsigned char* __restrict__ wT8) {
  __shared__ float tile[128][65];
  const int t = threadIdx.x;
  if (blockIdx.x < XB8) {
    size_t i = ((size_t)blockIdx.x * 256 + t) * 16;
    const float4* xp = (const float4*)(x + i);
    float4 f0 = xp[0], f1 = xp[1], f2 = xp[2], f3 = xp[3];
    int4 o;
    int r;
    r = __builtin_amdgcn_cvt_pk_fp8_f32(f0.x, f0.y, 0, false);
    r = __builtin_amdgcn_cvt_pk_fp8_f32(f0.z, f0.w, r, true);
    o.x = r;
    r = __builtin_amdgcn_cvt_pk_fp8_f32(f1.x, f1.y, 0, false);
    r = __builtin_amdgcn_cvt_pk_fp8_f32(f1.z, f1.w, r, true);
    o.y = r;
    r = __builtin_amdgcn_cvt_pk_fp8_f32(f2.x, f2.y, 0, false);
    r = __builtin_amdgcn_cvt_pk_fp8_f32(f2.z, f2.w, r, true);
    o.z = r;
    r = __builtin_amdgcn_cvt_pk_fp8_f32(f3.x, f3.y, 0, false);
    r = __builtin_amdgcn_cvt_pk_fp8_f32(f3.z, f3.w, r, true);
    o.w = r;
    *(int4*)(x8 + i) = o;
    return;
  }
  const int b = blockIdx.x - XB8;
  const int v0 = (b % (V_DIM / 64)) * 64;
  const int k0 = (b / (V_DIM / 64)) * 128;
  {
    const int vq = t & 15;    // float4 index (16 x 4 = 64 floats/row)
    const int kr = t >> 4;    // 0..15
#pragma unroll
    for (int p = 0; p < 128; p += 16) {
      float4 v = *(const float4*)(w + (size_t)(k0 + kr + p) * V_DIM + v0 + vq * 4);
      tile[kr + p][vq * 4 + 0] = v.x;
      tile[kr + p][vq * 4 + 1] = v.y;
      tile[kr + p][vq * 4 + 2] = v.z;
      tile[kr + p][vq * 4 + 3] = v.w;
    }
  }
  __syncthreads();
  {
    const int vr = t >> 2;    // 0..63
    const int kq2 = t & 3;
#pragma unroll
    for (int h = 0; h < 2; ++h) {
      const int d4 = kq2 + h * 4;   // int4 index within 128B k-run
      int4 o;
      int r;
#pragma unroll
      for (int d = 0; d < 4; ++d) {
        r = __builtin_amdgcn_cvt_pk_fp8_f32(tile[d4 * 16 + d * 4 + 0][vr],
                                            tile[d4 * 16 + d * 4 + 1][vr], 0, false);
        r = __builtin_amdgcn_cvt_pk_fp8_f32(tile[d4 * 16 + d * 4 + 2][vr],
                                            tile[d4 * 16 + d * 4 + 3][vr], r, true);
        ((int*)&o)[d] = r;
      }
      *(int4*)(wT8 + (size_t)(v0 + vr) * H_DIM + k0 + d4 * 16) = o;
    }
  }
}

// ------------- fused MX-fp8 GEMM + per-row max/sumexp ------------------------
// R11 LESSON: counted-vmcnt deep pipeline (279us) LOST to plain depth-1
// full-drain (R8, 254us) -> the drain was never the stall. Arithmetic:
// ~5360 cyc/tile measured vs MFMA 1105 + LDS ~1500 serial. The gap is
// 1-wave/SIMD serialization: MFMA blocks its wave (no async MFMA on CDNA),
// so with Occupancy 11% (1 block/CU in every config) NOTHING overlaps the
// MFMA issue latency, the ds_reads, the staging, or the barrier convoy.
// Schedule micro-opt within 1 wave/SIMD is a dead end.
//
// THIS ROUND (occupancy via geometry): 128x128 tile, STATIC 64 KB LDS
// (2 x 32KB dbuf) -> 2 blocks/CU (128 <= 160KB), 2 waves/SIMD. Wave-tile
// 64x64: acc[4][4]=64 VGPR + af[4]=32 + temps -> ~160 VGPR (2x160=320<=512
// per-SIMD pool OK). Static (not dynamic) LDS also rules out dynamic-alloc
// as the 1-block pin. Schedule: unchanged proven R8 depth-1 aged prefetch.
__global__ __launch_bounds__(256) void k_gemm_lse(const unsigned char* __restrict__ A,
                                                  const unsigned char* __restrict__ Bt,
                                                  float* __restrict__ m_part,
                                                  float* __restrict__ s_part) {
  __shared__ __align__(16) unsigned char sMem[2][2][16384];  // [buf][A/B] 64KB
#define SMA(buf) (&sMem[buf][0][0])
#define SMB(buf) (&sMem[buf][1][0])
  float* maxbuf = (float*)&sMem[0][0][0];       // alias: dead after K-loop
  float* sumbuf = (float*)&sMem[0][0][2048];

  const int tid = threadIdx.x;
  // bijective XCD swizzle: 8000 blocks, 8000 % 8 == 0 -> chunks of 1000/XCD.
  // rt fast within a chunk -> B panel (128KB) L2-resident across 32 blocks.
  const int wg = ((int)blockIdx.x & 7) * ((RT_NUM * CT_NUM) / 8) + ((int)blockIdx.x >> 3);
  const int rt = wg & (RT_NUM - 1);   // 32 (pow2)
  const int ct = wg >> 5;
  const int m0 = rt * BM;
  const int n0 = ct * BN;

  const int w = tid >> 6;
  const int l = tid & 63;
  const int wm = w >> 1;        // 0..1  (M: rows wm*64 .. +63)
  const int wn = w & 1;         // 0..1  (N: cols wn*64 .. +63)
  const int quad = l >> 4, lc = l & 15;

  f32x4 acc[4][4];
#pragma unroll
  for (int i = 0; i < 4; ++i)
#pragma unroll
    for (int j = 0; j < 4; ++j)
      acc[i][j] = (f32x4){0.f, 0.f, 0.f, 0.f};

  // staging: one issue = 256 thr x 16B = 4KB = 32 rows of 128B.
  // A (128 rows) = 4 issues, B = 4 issues; 8 glds/thread/tile.
  // Pre-swizzled global source column + linear LDS dest (m173).
  const int srow = tid >> 3;                               // 0..31
  const int scol = ((tid & 7) ^ (srow & 7)) * 16;
  const unsigned char* ga = A + (size_t)(m0 + srow) * H_DIM + scol;
  const unsigned char* gb = Bt + (size_t)(n0 + srow) * H_DIM + scol;
  const int dOff = tid * 16;

  // fragment read offsets (two swizzled b128 reads per frag; row&7 == lc&7)
  const int aoff = wm * 8192 + lc * 128;   // + i*2048
  const int boff = wn * 8192 + lc * 128;   // + j*2048
  const int sw0 = ((quad * 2) ^ (lc & 7)) * 16;
  const int sw1 = ((quad * 2 + 1) ^ (lc & 7)) * 16;

#define GLDS(gp, lp)                                                     \
  __builtin_amdgcn_global_load_lds(                                      \
      (const __attribute__((address_space(1))) void*)(gp),               \
      (__attribute__((address_space(3))) void*)(lp), 16, 0, 0)

#define STAGE8(buf, koff)                                                \
  do {                                                                   \
    _Pragma("unroll")                                                    \
    for (int i_ = 0; i_ < 4; ++i_)                                       \
      GLDS(ga + (size_t)i_ * 32 * H_DIM + (koff),                        \
           SMA(buf) + dOff + i_ * 4096);                                 \
    _Pragma("unroll")                                                    \
    for (int i_ = 0; i_ < 4; ++i_)                                       \
      GLDS(gb + (size_t)i_ * 32 * H_DIM + (koff),                        \
           SMB(buf) + dOff + i_ * 4096);                                 \
  } while (0)

#define LDA8(dst, buf, i)                                                \
  do {                                                                   \
    const unsigned char* p_ = SMA(buf) + (i) * 2048 + aoff;              \
    i32x4v lo_ = *(const i32x4v*)(p_ + sw0);                             \
    i32x4v hi_ = *(const i32x4v*)(p_ + sw1);                             \
    dst = __builtin_shufflevector(lo_, hi_, 0, 1, 2, 3, 4, 5, 6, 7);     \
  } while (0)

#define LDB8(dst, buf, j)                                                \
  do {                                                                   \
    const unsigned char* p_ = SMB(buf) + (j) * 2048 + boff;              \
    i32x4v lo_ = *(const i32x4v*)(p_ + sw0);                             \
    i32x4v hi_ = *(const i32x4v*)(p_ + sw1);                             \
    dst = __builtin_shufflevector(lo_, hi_, 0, 1, 2, 3, 4, 5, 6, 7);     \
  } while (0)

  // prologue: tile 0
  STAGE8(0, 0);
  __syncthreads();

#pragma unroll
  for (int kt = 0; kt < NKT; ++kt) {
    const int cur = kt & 1;
    if (kt < NKT - 1) STAGE8(cur ^ 1, (kt + 1) * BK);  // aged prefetch

    i32x8v af[4];
    LDA8(af[0], cur, 0); LDA8(af[1], cur, 1);
    LDA8(af[2], cur, 2); LDA8(af[3], cur, 3);
#pragma unroll
    for (int j = 0; j < 4; ++j) {
      i32x8v bfj;
      LDB8(bfj, cur, j);
#pragma unroll
      for (int i = 0; i < 4; ++i)
        acc[i][j] = __builtin_amdgcn_mfma_scale_f32_16x16x128_f8f6f4(
            af[i], bfj, acc[i][j], 0, 0, 0, SCALE1, 0, SCALE1);
    }
    __syncthreads();  // drains vmcnt (aged prefetch) + all waves' ds_reads;
                      // next iter may overwrite buf cur.
  }
#undef STAGE8
#undef GLDS
#undef LDA8
#undef LDB8

  // ---- epilogue: per-row max / sum-exp partials ----
  // C/D layout (shape-determined): col = lane&15, row = quad*4 + reg.
  // Global row of acc[i][*] reg r at lane(quad,lc): wm*64 + i*16 + quad*4 + r.
  float rmax[4][4];
#pragma unroll
  for (int i = 0; i < 4; ++i)
#pragma unroll
    for (int r = 0; r < 4; ++r) {
      float mx = fmaxf(fmaxf(acc[i][0][r], acc[i][1][r]),
                       fmaxf(acc[i][2][r], acc[i][3][r]));
#pragma unroll
      for (int off = 1; off < 16; off <<= 1)
        mx = fmaxf(mx, __shfl_xor(mx, off, 64));
      rmax[i][r] = mx;
    }
  // sMem alias safe: the loop's final __syncthreads passed (all reads drained)
  if (lc == 0) {
#pragma unroll
    for (int i = 0; i < 4; ++i)
#pragma unroll
      for (int r = 0; r < 4; ++r)
        maxbuf[(wm * 64 + i * 16 + quad * 4 + r) * 2 + wn] = rmax[i][r];
  }
  __syncthreads();
  float rowmax[4][4];
#pragma unroll
  for (int i = 0; i < 4; ++i)
#pragma unroll
    for (int r = 0; r < 4; ++r) {
      int row = wm * 64 + i * 16 + quad * 4 + r;
      rowmax[i][r] = fmaxf(maxbuf[row * 2], maxbuf[row * 2 + 1]);
    }
#pragma unroll
  for (int i = 0; i < 4; ++i)
#pragma unroll
    for (int r = 0; r < 4; ++r) {
      float s = __expf(acc[i][0][r] - rowmax[i][r]) + __expf(acc[i][1][r] - rowmax[i][r]) +
                __expf(acc[i][2][r] - rowmax[i][r]) + __expf(acc[i][3][r] - rowmax[i][r]);
#pragma unroll
      for (int off = 1; off < 16; off <<= 1)
        s += __shfl_xor(s, off, 64);
      if (lc == 0) sumbuf[(wm * 64 + i * 16 + quad * 4 + r) * 2 + wn] = s;
    }
  __syncthreads();
  if (wn == 0 && lc == 0) {
#pragma unroll
    for (int i = 0; i < 4; ++i)
#pragma unroll
      for (int r = 0; r < 4; ++r) {
        int row = wm * 64 + i * 16 + quad * 4 + r;
        size_t idx = (size_t)(m0 + row) * CT_NUM + ct;
        m_part[idx] = rowmax[i][r];
        s_part[idx] = sumbuf[row * 2] + sumbuf[row * 2 + 1];
      }
  }
#undef SMA
#undef SMB
}

// ------------- combine partials + target logit -> per-block partial sums ----
__global__ __launch_bounds__(256) void k_combine(const float* __restrict__ x,
                                                 const unsigned char* __restrict__ wT8,
                                                 const int* __restrict__ target,
                                                 const float* __restrict__ m_part,
                                                 const float* __restrict__ s_part,
                                                 float* __restrict__ blk_part) {
  __shared__ float red[8];
  const int wv = threadIdx.x >> 6;
  const int row = blockIdx.x * 4 + wv;  // one wave per row
  const int l = threadIdx.x & 63;
  float m = -INFINITY, s = 0.f;
  for (int ctb = l; ctb < CT_NUM; ctb += 64) {
    float mj = m_part[(size_t)row * CT_NUM + ctb];
    float sj = s_part[(size_t)row * CT_NUM + ctb];
    float M = fmaxf(m, mj);
    s = s * __expf(m - M) + sj * __expf(mj - M);
    m = M;
  }
#pragma unroll
  for (int off = 1; off < 64; off <<= 1) {
    float mo = __shfl_xor(m, off, 64);
    float so = __shfl_xor(s, off, 64);
    float M = fmaxf(m, mo);
    s = s * __expf(m - M) + so * __expf(mo - M);
    m = M;
  }
  float lse = m + logf(s);
  int tgt = target[row];
  bool valid = (tgt != IGNORE_INDEX);
  int st = valid ? tgt : 0;
  // target logit: x[row] fp32 . wT8[st] fp8 (16 bytes per lane)
  const float* xr = x + (size_t)row * H_DIM + l * 16;
  int4 wv4 = *(const int4*)(wT8 + (size_t)st * H_DIM + l * 16);
  float t = 0.f;
#define ACC_DW(dw, base)                                              \
  t += xr[base + 0] * __builtin_amdgcn_cvt_f32_fp8(dw, 0);            \
  t += xr[base + 1] * __builtin_amdgcn_cvt_f32_fp8(dw, 1);            \
  t += xr[base + 2] * __builtin_amdgcn_cvt_f32_fp8(dw, 2);            \
  t += xr[base + 3] * __builtin_amdgcn_cvt_f32_fp8(dw, 3);
  ACC_DW(wv4.x, 0)
  ACC_DW(wv4.y, 4)
  ACC_DW(wv4.z, 8)
  ACC_DW(wv4.w, 12)
#undef ACC_DW
#pragma unroll
  for (int off = 1; off < 64; off <<= 1)
    t += __shfl_xor(t, off, 64);
  if (l == 0) {
    red[wv * 2]     = valid ? (lse - t) : 0.f;
    red[wv * 2 + 1] = valid ? lse : 0.f;
  }
  __syncthreads();
  if (threadIdx.x == 0) {
    blk_part[blockIdx.x * 2]     = red[0] + red[2] + red[4] + red[6];
    blk_part[blockIdx.x * 2 + 1] = red[1] + red[3] + red[5] + red[7];
  }
}

// ------------- final single-block reduce -------
__global__ __launch_bounds__(256) void k_final(const float* __restrict__ bp,
                                               float* __restrict__ out) {
  __shared__ float ra[4], rb[4];
  float a = 0.f, b = 0.f;
  for (int i = threadIdx.x; i < N_ROWS / 4; i += 256) {
    a += bp[i * 2];
    b += bp[i * 2 + 1];
  }
#pragma unroll
  for (int off = 1; off < 64; off <<= 1) {
    a += __shfl_xor(a, off, 64);
    b += __shfl_xor(b, off, 64);
  }
  if ((threadIdx.x & 63) == 0) { ra[threadIdx.x >> 6] = a; rb[threadIdx.x >> 6] = b; }
  __syncthreads();
  if (threadIdx.x == 0) {
    out[0] = ra[0] + ra[1] + ra[2] + ra[3];
    out[1] = rb[0] + rb[1] + rb[2] + rb[3];
  }
}

extern "C" void kernel_launch(void* const* d_in, const int* in_sizes, int n_in,
                              void* d_out, int out_size, void* d_ws, size_t ws_size,
                              hipStream_t stream) {
  const float* x = (const float*)d_in[0];
  const float* w = (const float*)d_in[1];
  const int* target = (const int*)d_in[2];
  float* out = (float*)d_out;

  char* ws = (char*)d_ws;
  // ws layout:
  //   x8       : 4096*1024   =  4,194,304
  //   wT8      : 32000*1024  = 32,768,000
  //   m_part   : 4096*250*4  =  4,096,000
  //   s_part   : 4096*250*4  =  4,096,000
  //   blk_part : 1024*2*4    =      8,192
  unsigned char* x8 = (unsigned char*)ws;
  unsigned char* wT8 = (unsigned char*)(ws + 4194304);
  float* m_part = (float*)(ws + 4194304 + 32768000);
  float* s_part = (float*)(ws + 4194304 + 32768000 + 4096000);
  float* blk_part = (float*)(ws + 4194304 + 32768000 + 4096000 + 4096000);

  k_prep<<<dim3(XB8 + (V_DIM / 64) * (H_DIM / 128)), 256, 0, stream>>>(x, w, x8, wT8);
  k_gemm_lse<<<dim3(RT_NUM * CT_NUM), 256, 0, stream>>>(x8, wT8, m_part, s_part);
  k_combine<<<dim3(N_ROWS / 4), 256, 0, stream>>>(x, wT8, target, m_part, s_part, blk_part);
  k_final<<<dim3(1), 256, 0, stream>>>(blk_part, out);
}

// Round 18
// 447.941 us; speedup vs baseline: 1.0077x; 1.0077x over previous
//
#include <hip/hip_runtime.h>
#include <hip/hip_bf16.h>

typedef float f32x4 __attribute__((ext_vector_type(4)));
typedef int i32x4v __attribute__((ext_vector_type(4)));
typedef int i32x8v __attribute__((ext_vector_type(8)));

#define IGNORE_INDEX (-100)
#define N_ROWS 4096
#define H_DIM  1024
#define V_DIM  32000

#define BM 128
#define BN 128
#define BK 128                 /* fp8 elements = bytes; one mfma_scale K */
#define NKT (H_DIM / BK)       /* 8 */
#define CT_NUM (V_DIM / BN)    /* 250 */
#define RT_NUM (N_ROWS / BM)   /* 32 */
#define SCALE1 0x7f7f7f7f      /* 4x e8m0 = 127 -> x1.0 */

// ---------- fused prep: cast x -> fp8 (blocks < XB8) + transpose-cast w ----------
// R17 CHANGE: w-transpose retiled 128k x 64v -> 64k x 256v (float LDS tile).
// Old pattern read w in 256B chunks at 125KB stride (DRAM-hostile; suspected
// ~100us of the 197us non-GEMM residue). New: 1KB contiguous per row (4x),
// aligned float4 LDS stores, padded [64][264] readback (conflict-free),
// 64B-contiguous per-v-row writes. Outputs identical.
#define XB8 (N_ROWS * H_DIM / (256 * 16))  /* 1024 */
__global__ __launch_bounds__(256) void k_prep(const float* __restrict__ x,
                                              const float* __restrict__ w,
                                              unsigned char* __restrict__ x8,
                                              unsigned char* __restrict__ wT8) {
  __shared__ float tile2[64][264];   // 67.6 KB; row stride 1056B (16-aligned)
  const int t = threadIdx.x;
  if (blockIdx.x < XB8) {
    size_t i = ((size_t)blockIdx.x * 256 + t) * 16;
    const float4* xp = (const float4*)(x + i);
    float4 f0 = xp[0], f1 = xp[1], f2 = xp[2], f3 = xp[3];
    int4 o;
    int r;
    r = __builtin_amdgcn_cvt_pk_fp8_f32(f0.x, f0.y, 0, false);
    r = __builtin_amdgcn_cvt_pk_fp8_f32(f0.z, f0.w, r, true);
    o.x = r;
    r = __builtin_amdgcn_cvt_pk_fp8_f32(f1.x, f1.y, 0, false);
    r = __builtin_amdgcn_cvt_pk_fp8_f32(f1.z, f1.w, r, true);
    o.y = r;
    r = __builtin_amdgcn_cvt_pk_fp8_f32(f2.x, f2.y, 0, false);
    r = __builtin_amdgcn_cvt_pk_fp8_f32(f2.z, f2.w, r, true);
    o.z = r;
    r = __builtin_amdgcn_cvt_pk_fp8_f32(f3.x, f3.y, 0, false);
    r = __builtin_amdgcn_cvt_pk_fp8_f32(f3.z, f3.w, r, true);
    o.w = r;
    *(int4*)(x8 + i) = o;
    return;
  }
  const int b = blockIdx.x - XB8;
  const int v0 = (b % (V_DIM / 256)) * 256;   // 125 column panels
  const int k0 = (b / (V_DIM / 256)) * 64;    // 16 k-strips
  {
    const int vq = t & 63;    // float4 slot (64 x 4 = 256 floats/row)
    const int kr = t >> 6;    // 0..3
#pragma unroll
    for (int p = 0; p < 64; p += 4) {
      float4 v = *(const float4*)(w + (size_t)(k0 + kr + p) * V_DIM + v0 + vq * 4);
      *(float4*)&tile2[kr + p][vq * 4] = v;   // aligned (1056 % 16 == 0)
    }
  }
  __syncthreads();
  {
    const int vr = t;         // 0..255: one output v-row per thread
#pragma unroll
    for (int q = 0; q < 4; ++q) {
      int4 o;
      int r;
#pragma unroll
      for (int d = 0; d < 4; ++d) {
        const int kk = q * 16 + d * 4;
        r = __builtin_amdgcn_cvt_pk_fp8_f32(tile2[kk + 0][vr],
                                            tile2[kk + 1][vr], 0, false);
        r = __builtin_amdgcn_cvt_pk_fp8_f32(tile2[kk + 2][vr],
                                            tile2[kk + 3][vr], r, true);
        ((int*)&o)[d] = r;
      }
      *(int4*)(wT8 + (size_t)(v0 + vr) * H_DIM + k0 + q * 16) = o;
    }
  }
}

// ------------- fused MX-fp8 GEMM + per-row max/sumexp ------------------------
// R17 LESSON (GEMM frozen): R12 doubled occupancy (11->21%, 2 blocks/CU,
// VGPR 112) with MfmaUtil and time UNCHANGED (22%, 254us) vs R8 (1 block,
// 2x tile). Per-CU throughput invariant ~2440cyc/tile across geometry,
// pipeline depth (R11), and occupancy -> the binding resource is the shared
// per-CU LDS data pipe + fixed per-tile instruction stream, saturated in
// every config. GEMM structure frozen at this measured local optimum.
__global__ __launch_bounds__(256) void k_gemm_lse(const unsigned char* __restrict__ A,
                                                  const unsigned char* __restrict__ Bt,
                                                  float* __restrict__ m_part,
                                                  float* __restrict__ s_part) {
  __shared__ __align__(16) unsigned char sMem[2][2][16384];  // [buf][A/B] 64KB
#define SMA(buf) (&sMem[buf][0][0])
#define SMB(buf) (&sMem[buf][1][0])
  float* maxbuf = (float*)&sMem[0][0][0];       // alias: dead after K-loop
  float* sumbuf = (float*)&sMem[0][0][2048];

  const int tid = threadIdx.x;
  // bijective XCD swizzle: 8000 blocks, 8000 % 8 == 0 -> chunks of 1000/XCD.
  const int wg = ((int)blockIdx.x & 7) * ((RT_NUM * CT_NUM) / 8) + ((int)blockIdx.x >> 3);
  const int rt = wg & (RT_NUM - 1);   // 32 (pow2)
  const int ct = wg >> 5;
  const int m0 = rt * BM;
  const int n0 = ct * BN;

  const int w = tid >> 6;
  const int l = tid & 63;
  const int wm = w >> 1;        // 0..1  (M: rows wm*64 .. +63)
  const int wn = w & 1;         // 0..1  (N: cols wn*64 .. +63)
  const int quad = l >> 4, lc = l & 15;

  f32x4 acc[4][4];
#pragma unroll
  for (int i = 0; i < 4; ++i)
#pragma unroll
    for (int j = 0; j < 4; ++j)
      acc[i][j] = (f32x4){0.f, 0.f, 0.f, 0.f};

  const int srow = tid >> 3;                               // 0..31
  const int scol = ((tid & 7) ^ (srow & 7)) * 16;
  const unsigned char* ga = A + (size_t)(m0 + srow) * H_DIM + scol;
  const unsigned char* gb = Bt + (size_t)(n0 + srow) * H_DIM + scol;
  const int dOff = tid * 16;

  const int aoff = wm * 8192 + lc * 128;   // + i*2048
  const int boff = wn * 8192 + lc * 128;   // + j*2048
  const int sw0 = ((quad * 2) ^ (lc & 7)) * 16;
  const int sw1 = ((quad * 2 + 1) ^ (lc & 7)) * 16;

#define GLDS(gp, lp)                                                     \
  __builtin_amdgcn_global_load_lds(                                      \
      (const __attribute__((address_space(1))) void*)(gp),               \
      (__attribute__((address_space(3))) void*)(lp), 16, 0, 0)

#define STAGE8(buf, koff)                                                \
  do {                                                                   \
    _Pragma("unroll")                                                    \
    for (int i_ = 0; i_ < 4; ++i_)                                       \
      GLDS(ga + (size_t)i_ * 32 * H_DIM + (koff),                        \
           SMA(buf) + dOff + i_ * 4096);                                 \
    _Pragma("unroll")                                                    \
    for (int i_ = 0; i_ < 4; ++i_)                                       \
      GLDS(gb + (size_t)i_ * 32 * H_DIM + (koff),                        \
           SMB(buf) + dOff + i_ * 4096);                                 \
  } while (0)

#define LDA8(dst, buf, i)                                                \
  do {                                                                   \
    const unsigned char* p_ = SMA(buf) + (i) * 2048 + aoff;              \
    i32x4v lo_ = *(const i32x4v*)(p_ + sw0);                             \
    i32x4v hi_ = *(const i32x4v*)(p_ + sw1);                             \
    dst = __builtin_shufflevector(lo_, hi_, 0, 1, 2, 3, 4, 5, 6, 7);     \
  } while (0)

#define LDB8(dst, buf, j)                                                \
  do {                                                                   \
    const unsigned char* p_ = SMB(buf) + (j) * 2048 + boff;              \
    i32x4v lo_ = *(const i32x4v*)(p_ + sw0);                             \
    i32x4v hi_ = *(const i32x4v*)(p_ + sw1);                             \
    dst = __builtin_shufflevector(lo_, hi_, 0, 1, 2, 3, 4, 5, 6, 7);     \
  } while (0)

  // prologue: tile 0
  STAGE8(0, 0);
  __syncthreads();

#pragma unroll
  for (int kt = 0; kt < NKT; ++kt) {
    const int cur = kt & 1;
    if (kt < NKT - 1) STAGE8(cur ^ 1, (kt + 1) * BK);  // aged prefetch

    i32x8v af[4];
    LDA8(af[0], cur, 0); LDA8(af[1], cur, 1);
    LDA8(af[2], cur, 2); LDA8(af[3], cur, 3);
#pragma unroll
    for (int j = 0; j < 4; ++j) {
      i32x8v bfj;
      LDB8(bfj, cur, j);
#pragma unroll
      for (int i = 0; i < 4; ++i)
        acc[i][j] = __builtin_amdgcn_mfma_scale_f32_16x16x128_f8f6f4(
            af[i], bfj, acc[i][j], 0, 0, 0, SCALE1, 0, SCALE1);
    }
    __syncthreads();  // drains vmcnt (aged prefetch) + all waves' ds_reads
  }
#undef STAGE8
#undef GLDS
#undef LDA8
#undef LDB8

  // ---- epilogue: per-row max / sum-exp partials ----
  float rmax[4][4];
#pragma unroll
  for (int i = 0; i < 4; ++i)
#pragma unroll
    for (int r = 0; r < 4; ++r) {
      float mx = fmaxf(fmaxf(acc[i][0][r], acc[i][1][r]),
                       fmaxf(acc[i][2][r], acc[i][3][r]));
#pragma unroll
      for (int off = 1; off < 16; off <<= 1)
        mx = fmaxf(mx, __shfl_xor(mx, off, 64));
      rmax[i][r] = mx;
    }
  if (lc == 0) {
#pragma unroll
    for (int i = 0; i < 4; ++i)
#pragma unroll
      for (int r = 0; r < 4; ++r)
        maxbuf[(wm * 64 + i * 16 + quad * 4 + r) * 2 + wn] = rmax[i][r];
  }
  __syncthreads();
  float rowmax[4][4];
#pragma unroll
  for (int i = 0; i < 4; ++i)
#pragma unroll
    for (int r = 0; r < 4; ++r) {
      int row = wm * 64 + i * 16 + quad * 4 + r;
      rowmax[i][r] = fmaxf(maxbuf[row * 2], maxbuf[row * 2 + 1]);
    }
#pragma unroll
  for (int i = 0; i < 4; ++i)
#pragma unroll
    for (int r = 0; r < 4; ++r) {
      float s = __expf(acc[i][0][r] - rowmax[i][r]) + __expf(acc[i][1][r] - rowmax[i][r]) +
                __expf(acc[i][2][r] - rowmax[i][r]) + __expf(acc[i][3][r] - rowmax[i][r]);
#pragma unroll
      for (int off = 1; off < 16; off <<= 1)
        s += __shfl_xor(s, off, 64);
      if (lc == 0) sumbuf[(wm * 64 + i * 16 + quad * 4 + r) * 2 + wn] = s;
    }
  __syncthreads();
  if (wn == 0 && lc == 0) {
#pragma unroll
    for (int i = 0; i < 4; ++i)
#pragma unroll
      for (int r = 0; r < 4; ++r) {
        int row = wm * 64 + i * 16 + quad * 4 + r;
        size_t idx = (size_t)(m0 + row) * CT_NUM + ct;
        m_part[idx] = rowmax[i][r];
        s_part[idx] = sumbuf[row * 2] + sumbuf[row * 2 + 1];
      }
  }
#undef SMA
#undef SMB
}

// ------------- combine partials + target logit -> per-block partial sums ----
__global__ __launch_bounds__(256) void k_combine(const float* __restrict__ x,
                                                 const unsigned char* __restrict__ wT8,
                                                 const int* __restrict__ target,
                                                 const float* __restrict__ m_part,
                                                 const float* __restrict__ s_part,
                                                 float* __restrict__ blk_part) {
  __shared__ float red[8];
  const int wv = threadIdx.x >> 6;
  const int row = blockIdx.x * 4 + wv;  // one wave per row
  const int l = threadIdx.x & 63;
  float m = -INFINITY, s = 0.f;
  for (int ctb = l; ctb < CT_NUM; ctb += 64) {
    float mj = m_part[(size_t)row * CT_NUM + ctb];
    float sj = s_part[(size_t)row * CT_NUM + ctb];
    float M = fmaxf(m, mj);
    s = s * __expf(m - M) + sj * __expf(mj - M);
    m = M;
  }
#pragma unroll
  for (int off = 1; off < 64; off <<= 1) {
    float mo = __shfl_xor(m, off, 64);
    float so = __shfl_xor(s, off, 64);
    float M = fmaxf(m, mo);
    s = s * __expf(m - M) + so * __expf(mo - M);
    m = M;
  }
  float lse = m + logf(s);
  int tgt = target[row];
  bool valid = (tgt != IGNORE_INDEX);
  int st = valid ? tgt : 0;
  // target logit: x[row] fp32 . wT8[st] fp8 (16 bytes per lane)
  const float* xr = x + (size_t)row * H_DIM + l * 16;
  int4 wv4 = *(const int4*)(wT8 + (size_t)st * H_DIM + l * 16);
  float t = 0.f;
#define ACC_DW(dw, base)                                              \
  t += xr[base + 0] * __builtin_amdgcn_cvt_f32_fp8(dw, 0);            \
  t += xr[base + 1] * __builtin_amdgcn_cvt_f32_fp8(dw, 1);            \
  t += xr[base + 2] * __builtin_amdgcn_cvt_f32_fp8(dw, 2);            \
  t += xr[base + 3] * __builtin_amdgcn_cvt_f32_fp8(dw, 3);
  ACC_DW(wv4.x, 0)
  ACC_DW(wv4.y, 4)
  ACC_DW(wv4.z, 8)
  ACC_DW(wv4.w, 12)
#undef ACC_DW
#pragma unroll
  for (int off = 1; off < 64; off <<= 1)
    t += __shfl_xor(t, off, 64);
  if (l == 0) {
    red[wv * 2]     = valid ? (lse - t) : 0.f;
    red[wv * 2 + 1] = valid ? lse : 0.f;
  }
  __syncthreads();
  if (threadIdx.x == 0) {
    blk_part[blockIdx.x * 2]     = red[0] + red[2] + red[4] + red[6];
    blk_part[blockIdx.x * 2 + 1] = red[1] + red[3] + red[5] + red[7];
  }
}

// ------------- final single-block reduce -------
__global__ __launch_bounds__(256) void k_final(const float* __restrict__ bp,
                                               float* __restrict__ out) {
  __shared__ float ra[4], rb[4];
  float a = 0.f, b = 0.f;
  for (int i = threadIdx.x; i < N_ROWS / 4; i += 256) {
    a += bp[i * 2];
    b += bp[i * 2 + 1];
  }
#pragma unroll
  for (int off = 1; off < 64; off <<= 1) {
    a += __shfl_xor(a, off, 64);
    b += __shfl_xor(b, off, 64);
  }
  if ((threadIdx.x & 63) == 0) { ra[threadIdx.x >> 6] = a; rb[threadIdx.x >> 6] = b; }
  __syncthreads();
  if (threadIdx.x == 0) {
    out[0] = ra[0] + ra[1] + ra[2] + ra[3];
    out[1] = rb[0] + rb[1] + rb[2] + rb[3];
  }
}

extern "C" void kernel_launch(void* const* d_in, const int* in_sizes, int n_in,
                              void* d_out, int out_size, void* d_ws, size_t ws_size,
                              hipStream_t stream) {
  const float* x = (const float*)d_in[0];
  const float* w = (const float*)d_in[1];
  const int* target = (const int*)d_in[2];
  float* out = (float*)d_out;

  char* ws = (char*)d_ws;
  // ws layout:
  //   x8       : 4096*1024   =  4,194,304
  //   wT8      : 32000*1024  = 32,768,000
  //   m_part   : 4096*250*4  =  4,096,000
  //   s_part   : 4096*250*4  =  4,096,000
  //   blk_part : 1024*2*4    =      8,192
  unsigned char* x8 = (unsigned char*)ws;
  unsigned char* wT8 = (unsigned char*)(ws + 4194304);
  float* m_part = (float*)(ws + 4194304 + 32768000);
  float* s_part = (float*)(ws + 4194304 + 32768000 + 4096000);
  float* blk_part = (float*)(ws + 4194304 + 32768000 + 4096000 + 4096000);

  k_prep<<<dim3(XB8 + (V_DIM / 256) * (H_DIM / 64)), 256, 0, stream>>>(x, w, x8, wT8);
  k_gemm_lse<<<dim3(RT_NUM * CT_NUM), 256, 0, stream>>>(x8, wT8, m_part, s_part);
  k_combine<<<dim3(N_ROWS / 4), 256, 0, stream>>>(x, wT8, target, m_part, s_part, blk_part);
  k_final<<<dim3(1), 256, 0, stream>>>(blk_part, out);
}